// Round 11
// baseline (3411.456 us; speedup 1.0000x reference)
//
#include <hip/hip_runtime.h>
#include <hip/hip_bf16.h>
#include <math.h>

// Problem constants
// B=32, T=12, N=2048, C=1, D=10, K=2, H=32
#define NNODE 2048
#define NB 32
#define NT 12
#define NH 32
#define ND 10
#define NCOL 1024          // h columns
#define NCX 384            // (t,b) x columns
#define KPAD 96            // gconv K = 66, zero-padded to 3 MFMA k-tiles
#define GPAD 104           // LDS row stride (halfs) for cat tiles
#define WPAD 98            // LDS row stride for wg/wu transpose

#define ASCALE 256.0f
#define AINV 0.00390625f

#define KCHUNK 512
#define Y1S ((size_t)NNODE * NCOL)
#define AXPS ((size_t)NNODE * NCX)

typedef _Float16 half8 __attribute__((ext_vector_type(8)));
typedef float floatx4 __attribute__((ext_vector_type(4)));

#define AS1 __attribute__((address_space(1)))
#define AS3 __attribute__((address_space(3)))
__device__ __forceinline__ void gload16(const _Float16* g, _Float16* l) {
    __builtin_amdgcn_global_load_lds((const AS1 unsigned int*)(g),
                                     (AS3 unsigned int*)(l), 16, 0, 0);
}

// ---------------- workspace layout (float slots) ----------------
constexpr size_t OFF_AH  = 0;
constexpr size_t OFF_WGT = OFF_AH + 2097152u;
constexpr size_t OFF_WUT = OFF_WGT + 6291456u;
constexpr size_t OFF_BG  = OFF_WUT + 3145728u;
constexpr size_t OFF_BU  = OFF_BG + 131072u;
constexpr size_t OFF_XT  = OFF_BU + 65536u;
constexpr size_t OFF_X2T = OFF_XT + 1048576u;
constexpr size_t OFF_SXT = OFF_X2T + 1048576u;
constexpr size_t OFF_HS  = OFF_SXT + 393216u;
constexpr size_t OFF_Y   = OFF_HS + 2097152u;
constexpr size_t OFF_AXP = OFF_Y + 4194304u;
constexpr size_t OFF_R   = OFF_AXP + 1572864u;
constexpr size_t OFF_ZH  = OFF_R + 1048576u;
constexpr size_t OFF_BAR = OFF_ZH + 1048576u;   // 2 unsigneds
// end = 24,182,786 floats = ~96.7 MB

// ---------------- manual grid barrier (sense-reversing, agent scope) ----------------
__device__ __forceinline__ void gbar(unsigned* bar, int nb) {
    __syncthreads();
    if (threadIdx.x == 0) {
        unsigned g = __hip_atomic_load(bar + 1, __ATOMIC_RELAXED, __HIP_MEMORY_SCOPE_AGENT);
        unsigned a = __hip_atomic_fetch_add(bar, 1u, __ATOMIC_ACQ_REL, __HIP_MEMORY_SCOPE_AGENT);
        if (a == (unsigned)nb - 1u) {
            __hip_atomic_store(bar, 0u, __ATOMIC_RELAXED, __HIP_MEMORY_SCOPE_AGENT);
            __hip_atomic_store(bar + 1, g + 1u, __ATOMIC_RELEASE, __HIP_MEMORY_SCOPE_AGENT);
        } else {
            while (__hip_atomic_load(bar + 1, __ATOMIC_ACQUIRE, __HIP_MEMORY_SCOPE_AGENT) == g)
                __builtin_amdgcn_s_sleep(2);
        }
    }
    __syncthreads();
}

__global__ void bar_init(unsigned* bar) {
    __hip_atomic_store(bar, 0u, __ATOMIC_RELEASE, __HIP_MEMORY_SCOPE_AGENT);
    __hip_atomic_store(bar + 1, 0u, __ATOMIC_RELEASE, __HIP_MEMORY_SCOPE_AGENT);
}

// ---------------- A = softmax(relu(E E^T), axis=1) * ASCALE, fp16 ----------------
__global__ __launch_bounds__(256) void adj_kernel(const float* __restrict__ E,
                                                  _Float16* __restrict__ Ah) {
    __shared__ float En[ND];
    __shared__ float red[256];
    const int n = blockIdx.x;
    const int t = threadIdx.x;
    if (t < ND) En[t] = E[n * ND + t];
    __syncthreads();
    float v[8];
    float mx = 0.f;
#pragma unroll
    for (int i = 0; i < 8; ++i) {
        const int m = t + i * 256;
        float acc = 0.f;
#pragma unroll
        for (int d = 0; d < ND; ++d) acc += En[d] * E[m * ND + d];
        acc = fmaxf(acc, 0.f);
        v[i] = acc;
        mx = fmaxf(mx, acc);
    }
    red[t] = mx;
    __syncthreads();
    for (int s = 128; s > 0; s >>= 1) {
        if (t < s) red[t] = fmaxf(red[t], red[t + s]);
        __syncthreads();
    }
    mx = red[0];
    __syncthreads();
    float sum = 0.f;
#pragma unroll
    for (int i = 0; i < 8; ++i) {
        v[i] = expf(v[i] - mx);
        sum += v[i];
    }
    red[t] = sum;
    __syncthreads();
    for (int s = 128; s > 0; s >>= 1) {
        if (t < s) red[t] += red[t + s];
        __syncthreads();
    }
    const float inv = ASCALE / red[0];
#pragma unroll
    for (int i = 0; i < 8; ++i)
        Ah[(size_t)n * NNODE + t + i * 256] = (_Float16)(v[i] * inv);
}

// ---------------- per-node weights -> [n][o][k] via LDS transpose ----------------
__global__ __launch_bounds__(256) void wg_kernel(const float* __restrict__ E,
                                                 const float* __restrict__ gW,
                                                 _Float16* __restrict__ Wgt) {
    __shared__ float Es[ND];
    __shared__ _Float16 Wl[64 * WPAD];
    const int n = blockIdx.x, t = threadIdx.x;
    if (t < ND) Es[t] = E[n * ND + t];
    for (int i = t; i < 64 * WPAD / 2; i += 256) ((unsigned*)Wl)[i] = 0u;
    __syncthreads();
    for (int rem = t; rem < 4224; rem += 256) {
        float acc = 0.f;
#pragma unroll
        for (int d = 0; d < ND; ++d) acc += Es[d] * gW[d * 4224 + rem];
        const int kk = rem / 2112, r2 = rem % 2112;
        const int i = r2 >> 6, o = r2 & 63;
        Wl[o * WPAD + kk * 33 + i] = (_Float16)acc;
    }
    __syncthreads();
    const unsigned* wl = (const unsigned*)Wl;
    unsigned* dst = (unsigned*)(Wgt + (size_t)n * 6144);
    for (int idx = t; idx < 64 * 48; idx += 256) {
        const int o = idx / 48, j = idx % 48;
        dst[idx] = wl[o * (WPAD / 2) + j];
    }
}

__global__ __launch_bounds__(256) void wu_kernel(const float* __restrict__ E,
                                                 const float* __restrict__ uW,
                                                 _Float16* __restrict__ Wut) {
    __shared__ float Es[ND];
    __shared__ _Float16 Wl[32 * WPAD];
    const int n = blockIdx.x, t = threadIdx.x;
    if (t < ND) Es[t] = E[n * ND + t];
    for (int i = t; i < 32 * WPAD / 2; i += 256) ((unsigned*)Wl)[i] = 0u;
    __syncthreads();
    for (int rem = t; rem < 2112; rem += 256) {
        float acc = 0.f;
#pragma unroll
        for (int d = 0; d < ND; ++d) acc += Es[d] * uW[d * 2112 + rem];
        const int kk = rem / 1056, r2 = rem % 1056;
        const int i = r2 >> 5, o = r2 & 31;
        Wl[o * WPAD + kk * 33 + i] = (_Float16)acc;
    }
    __syncthreads();
    const unsigned* wl = (const unsigned*)Wl;
    unsigned* dst = (unsigned*)(Wut + (size_t)n * 3072);
    for (int idx = t; idx < 32 * 48; idx += 256) {
        const int o = idx / 48, j = idx % 48;
        dst[idx] = wl[o * (WPAD / 2) + j];
    }
}

__global__ __launch_bounds__(256) void bias_kernel(const float* __restrict__ E,
                                                   const float* __restrict__ gb,
                                                   const float* __restrict__ ub,
                                                   float* __restrict__ bg,
                                                   float* __restrict__ bu) {
    const int idx = blockIdx.x * 256 + threadIdx.x;
    if (idx < NNODE * 64) {
        const int n = idx >> 6, o = idx & 63;
        float acc = 0.f;
#pragma unroll
        for (int d = 0; d < ND; ++d) acc += E[n * ND + d] * gb[d * 64 + o];
        bg[idx] = acc;
    } else if (idx < NNODE * 64 + NNODE * 32) {
        const int j = idx - NNODE * 64;
        const int n = j >> 5, o = j & 31;
        float acc = 0.f;
#pragma unroll
        for (int d = 0; d < ND; ++d) acc += E[n * ND + d] * ub[d * 32 + o];
        bu[j] = acc;
    }
}

// ---------------- mm tile task (device body; task = R9 bid decode) ----------------
__device__ __forceinline__ void mm_tile(const _Float16* __restrict__ Ah,
                                        const _Float16* __restrict__ XT,
                                        _Float16* __restrict__ Y, int nct,
                                        int task, int t, _Float16* As, _Float16* Bs) {
    const int xcd = task & 7;
    const int kz = xcd >> 1;
    const int s = (task >> 3) * 2 + (xcd & 1);
    const int m0 = (s & 15) * 128;
    const int c0 = (s >> 4) * 128;
    const int ncols = nct << 7;
    _Float16* __restrict__ Yp = Y + (size_t)kz * NNODE * ncols;
    const int lane = t & 63;
    const int w = t >> 6;
    const int wm = (w & 1) * 64;
    const int wn = (w >> 1) * 64;
    const int lm = lane & 15;
    const int q = lane >> 4;

    const int srow = w * 32 + (lane >> 2);
    const int sq = (lane & 3) ^ ((lane >> 3) & 3);
    const _Float16* gA = Ah + (size_t)(m0 + srow) * NNODE + kz * KCHUNK + sq * 8;
    const _Float16* gB = XT + (size_t)(c0 + srow) * NNODE + kz * KCHUNK + sq * 8;
    _Float16* lA = As + w * 1024;
    _Float16* lB = Bs + w * 1024;
    const int fp = (q ^ ((lm >> 1) & 3)) * 8;

    floatx4 acc[4][4] = {};

    for (int kt = 0; kt < KCHUNK; kt += 32) {
        gload16(gA, lA);
        gload16(gA + 16 * NNODE, lA + 512);
        gload16(gB, lB);
        gload16(gB + 16 * NNODE, lB + 512);
        gA += 32;
        gB += 32;
        __syncthreads();
        half8 af[4], bf[4];
#pragma unroll
        for (int mt = 0; mt < 4; ++mt)
            af[mt] = *(const half8*)&As[(wm + mt * 16 + lm) * 32 + fp];
#pragma unroll
        for (int nt = 0; nt < 4; ++nt)
            bf[nt] = *(const half8*)&Bs[(wn + nt * 16 + lm) * 32 + fp];
#pragma unroll
        for (int mt = 0; mt < 4; ++mt)
#pragma unroll
            for (int nt = 0; nt < 4; ++nt)
                acc[mt][nt] = __builtin_amdgcn_mfma_f32_16x16x32_f16(
                    af[mt], bf[nt], acc[mt][nt], 0, 0, 0);
        __syncthreads();
    }
#pragma unroll
    for (int mt = 0; mt < 4; ++mt) {
#pragma unroll
        for (int nt = 0; nt < 4; ++nt) {
            const int row = m0 + wm + mt * 16 + q * 4;
            const int col = c0 + wn + nt * 16 + lm;
#pragma unroll
            for (int r = 0; r < 4; ++r)
                Yp[(size_t)(row + r) * ncols + col] = (_Float16)(acc[mt][nt][r] * AINV);
        }
    }
}

#define CAT(nd, b, i) cat[((nd) * 32 + (b)) * GPAD + (i)]

// ---------------- persistent megakernel (normal launch + manual grid barrier) ----------
__global__ __launch_bounds__(256, 2) void mega_kernel(
    const float* __restrict__ src, const _Float16* __restrict__ Ah,
    const _Float16* __restrict__ Wgt, const _Float16* __restrict__ Wut,
    const float* __restrict__ bg, const float* __restrict__ bu,
    const float* __restrict__ cw, const float* __restrict__ cb,
    _Float16* __restrict__ XT, _Float16* __restrict__ X2T,
    _Float16* __restrict__ SXT, float* __restrict__ Hs,
    _Float16* __restrict__ Y, _Float16* __restrict__ AXP,
    _Float16* __restrict__ rbuf, _Float16* __restrict__ zh,
    float* __restrict__ out, unsigned* bar, int nb) {
    __shared__ __align__(16) _Float16 smem[4 * 32 * GPAD];  // 26,624 B union
    _Float16* As = smem;
    _Float16* Bs = smem + 4096;
    _Float16* cat = smem;
    const int t = threadIdx.x;
    const int bid = blockIdx.x;
    const int w = t >> 6, lane = t & 63, lm = lane & 15, q = lane >> 4;

    // ---- prologue: XT=0, Hs=0, SXT from src ----
    {
        unsigned* p = (unsigned*)XT;
        for (int idx = bid * 256 + t; idx < 1048576; idx += nb * 256) p[idx] = 0u;
        unsigned* ph = (unsigned*)Hs;
        for (int idx = bid * 256 + t; idx < 2097152; idx += nb * 256) ph[idx] = 0u;
        for (int idx = bid * 256 + t; idx < NCX * NNODE; idx += nb * 256) {
            const int col = idx >> 11, n = idx & 2047;
            const int tt = col >> 5, b = col & 31;
            SXT[idx] = (_Float16)src[((size_t)b * NT + tt) * NNODE + n];
        }
    }
    gbar(bar, nb);

    // ---- AXP = A @ SXT (192 tasks) ----
    for (int task = bid; task < 192; task += nb)
        mm_tile(Ah, SXT, AXP, 3, task, t, As, Bs);
    gbar(bar, nb);

    for (int step = 0; step < NT; ++step) {
        // ---- mm1: Y = A @ XT (512 tasks) ----
        for (int task = bid; task < 512; task += nb)
            mm_tile(Ah, XT, Y, 8, task, t, As, Bs);
        gbar(bar, nb);

        // ---- gate (512 node-groups of 4) ----
        for (int g = bid; g < 512; g += nb) {
            const int n0 = g * 4;
            {
                const int pair = t >> 1, which = t & 1;
                const int nd = pair >> 5, b = pair & 31;
                const int n1 = n0 + nd;
                if (which == 0) {
                    CAT(nd, b, 0) = (_Float16)src[((size_t)b * NT + step) * NNODE + n1];
                    const float* hp = Hs + (size_t)n1 * 1024 + b * 32;
#pragma unroll
                    for (int i = 0; i < 32; ++i) CAT(nd, b, 1 + i) = (_Float16)hp[i];
#pragma unroll
                    for (int i = 66; i < KPAD; i += 2) *(unsigned*)&CAT(nd, b, i) = 0u;
                } else {
                    const _Float16* ax = AXP + (size_t)n1 * NCX + step * 32 + b;
                    CAT(nd, b, 33) = (_Float16)((float)ax[0] + (float)ax[AXPS] +
                                                (float)ax[2 * AXPS] + (float)ax[3 * AXPS]);
                    const _Float16* yp = Y + (size_t)n1 * NCOL + b * 32;
#pragma unroll
                    for (int i = 0; i < 32; ++i) {
                        const float sv = (float)yp[i] + (float)yp[Y1S + i] +
                                         (float)yp[2 * Y1S + i] + (float)yp[3 * Y1S + i];
                        CAT(nd, b, 34 + i) = (_Float16)sv;
                    }
                }
            }
            __syncthreads();
            const int n = n0 + w;
            const _Float16* Wn = Wgt + (size_t)n * 6144;
            floatx4 acc[2][4] = {};
#pragma unroll
            for (int kt = 0; kt < 3; ++kt) {
                half8 af[2], bf[4];
#pragma unroll
                for (int mt = 0; mt < 2; ++mt)
                    af[mt] = *(const half8*)&CAT(w, mt * 16 + lm, kt * 32 + q * 8);
#pragma unroll
                for (int nt = 0; nt < 4; ++nt)
                    bf[nt] = *(const half8*)(Wn + (nt * 16 + lm) * KPAD + kt * 32 + q * 8);
#pragma unroll
                for (int mt = 0; mt < 2; ++mt)
#pragma unroll
                    for (int nt = 0; nt < 4; ++nt)
                        acc[mt][nt] = __builtin_amdgcn_mfma_f32_16x16x32_f16(
                            af[mt], bf[nt], acc[mt][nt], 0, 0, 0);
            }
#pragma unroll
            for (int nt = 0; nt < 4; ++nt) {
                const int o = nt * 16 + lm;
                const float bias = bg[n * 64 + o];
#pragma unroll
                for (int mt = 0; mt < 2; ++mt) {
#pragma unroll
                    for (int r = 0; r < 4; ++r) {
                        const int b = mt * 16 + q * 4 + r;
                        const float s = 1.f / (1.f + expf(-(acc[mt][nt][r] + bias)));
                        if (o < 32) {
                            const float hold = Hs[(size_t)n * 1024 + b * 32 + o];
                            const _Float16 zv = (_Float16)(s * hold);
                            zh[(size_t)n * 1024 + b * 32 + o] = zv;
                            X2T[(size_t)(b * 32 + o) * NNODE + n] = zv;
                        } else {
                            rbuf[(size_t)n * 1024 + b * 32 + (o - 32)] = (_Float16)s;
                        }
                    }
                }
            }
            __syncthreads();  // cat WAR across strided iterations
        }
        gbar(bar, nb);

        // ---- mm2: Y = A @ X2T ----
        for (int task = bid; task < 512; task += nb)
            mm_tile(Ah, X2T, Y, 8, task, t, As, Bs);
        gbar(bar, nb);

        // ---- update ----
        for (int g = bid; g < 512; g += nb) {
            const int n0 = g * 4;
            {
                const int pair = t >> 1, which = t & 1;
                const int nd = pair >> 5, b = pair & 31;
                const int n1 = n0 + nd;
                if (which == 0) {
                    CAT(nd, b, 0) = (_Float16)src[((size_t)b * NT + step) * NNODE + n1];
                    const _Float16* zp = zh + (size_t)n1 * 1024 + b * 32;
#pragma unroll
                    for (int i = 0; i < 32; ++i) CAT(nd, b, 1 + i) = zp[i];
#pragma unroll
                    for (int i = 66; i < KPAD; i += 2) *(unsigned*)&CAT(nd, b, i) = 0u;
                } else {
                    const _Float16* ax = AXP + (size_t)n1 * NCX + step * 32 + b;
                    CAT(nd, b, 33) = (_Float16)((float)ax[0] + (float)ax[AXPS] +
                                                (float)ax[2 * AXPS] + (float)ax[3 * AXPS]);
                    const _Float16* yp = Y + (size_t)n1 * NCOL + b * 32;
#pragma unroll
                    for (int i = 0; i < 32; ++i) {
                        const float sv = (float)yp[i] + (float)yp[Y1S + i] +
                                         (float)yp[2 * Y1S + i] + (float)yp[3 * Y1S + i];
                        CAT(nd, b, 34 + i) = (_Float16)sv;
                    }
                }
            }
            __syncthreads();
            const int n = n0 + w;
            const _Float16* Wn = Wut + (size_t)n * 3072;
            floatx4 acc[2][2] = {};
#pragma unroll
            for (int kt = 0; kt < 3; ++kt) {
                half8 af[2], bf[2];
#pragma unroll
                for (int mt = 0; mt < 2; ++mt)
                    af[mt] = *(const half8*)&CAT(w, mt * 16 + lm, kt * 32 + q * 8);
#pragma unroll
                for (int nt = 0; nt < 2; ++nt)
                    bf[nt] = *(const half8*)(Wn + (nt * 16 + lm) * KPAD + kt * 32 + q * 8);
#pragma unroll
                for (int mt = 0; mt < 2; ++mt)
#pragma unroll
                    for (int nt = 0; nt < 2; ++nt)
                        acc[mt][nt] = __builtin_amdgcn_mfma_f32_16x16x32_f16(
                            af[mt], bf[nt], acc[mt][nt], 0, 0, 0);
            }
#pragma unroll
            for (int nt = 0; nt < 2; ++nt) {
                const int o = nt * 16 + lm;
                const float bias = bu[n * 32 + o];
#pragma unroll
                for (int mt = 0; mt < 2; ++mt) {
#pragma unroll
                    for (int r = 0; r < 4; ++r) {
                        const int b = mt * 16 + q * 4 + r;
                        const float hc = tanhf(acc[mt][nt][r] + bias);
                        const float rr = (float)rbuf[(size_t)n * 1024 + b * 32 + o];
                        const size_t hidx = (size_t)n * 1024 + b * 32 + o;
                        const float hnew = rr * Hs[hidx] + (1.f - rr) * hc;
                        Hs[hidx] = hnew;
                        XT[(size_t)(b * 32 + o) * NNODE + n] = (_Float16)hnew;
                    }
                }
            }
            __syncthreads();
        }
        gbar(bar, nb);
    }

    // ---- out ----
    for (int p = bid * 256 + t; p < NNODE * NB * NT; p += nb * 256) {
        const int n = p / 384, rem = p % 384;
        const int b = rem / NT, tt = rem % NT;
        float acc = cb[tt];
        const float* hp = Hs + (size_t)n * 1024 + b * 32;
#pragma unroll
        for (int j = 0; j < NH; ++j) acc += hp[j] * cw[tt * 32 + j];
        out[(size_t)b * NNODE * NT + (size_t)n * NT + tt] = acc;
    }
}

extern "C" void kernel_launch(void* const* d_in, const int* in_sizes, int n_in,
                              void* d_out, int out_size, void* d_ws, size_t ws_size,
                              hipStream_t stream) {
    const float* src  = (const float*)d_in[0];
    const float* E    = (const float*)d_in[1];
    const float* gW   = (const float*)d_in[2];
    const float* gb   = (const float*)d_in[3];
    const float* uW   = (const float*)d_in[4];
    const float* ub   = (const float*)d_in[5];
    const float* cw   = (const float*)d_in[6];
    const float* cb   = (const float*)d_in[7];
    float* out = (float*)d_out;

    float* ws = (float*)d_ws;
    _Float16* Ah  = (_Float16*)(ws + OFF_AH);
    _Float16* Wgt = (_Float16*)(ws + OFF_WGT);
    _Float16* Wut = (_Float16*)(ws + OFF_WUT);
    float* bg  = ws + OFF_BG;
    float* bu  = ws + OFF_BU;
    _Float16* XT  = (_Float16*)(ws + OFF_XT);
    _Float16* X2T = (_Float16*)(ws + OFF_X2T);
    _Float16* SXT = (_Float16*)(ws + OFF_SXT);
    float* Hs  = ws + OFF_HS;
    _Float16* Y   = (_Float16*)(ws + OFF_Y);
    _Float16* AXP = (_Float16*)(ws + OFF_AXP);
    _Float16* rb  = (_Float16*)(ws + OFF_R);
    _Float16* zh  = (_Float16*)(ws + OFF_ZH);
    unsigned* bar = (unsigned*)(ws + OFF_BAR);

    adj_kernel<<<NNODE, 256, 0, stream>>>(E, Ah);
    wg_kernel<<<NNODE, 256, 0, stream>>>(E, gW, Wgt);
    wu_kernel<<<NNODE, 256, 0, stream>>>(E, uW, Wut);
    bias_kernel<<<(NNODE * 96 + 255) / 256, 256, 0, stream>>>(E, gb, ub, bg, bu);
    bar_init<<<1, 1, 0, stream>>>(bar);

    // co-residency-safe grid size (occupancy query is not a stream op)
    int occ = 0;
    hipOccupancyMaxActiveBlocksPerMultiprocessor(&occ, mega_kernel, 256, 0);
    const int nb = (occ >= 2) ? 512 : 256;

    mega_kernel<<<nb, 256, 0, stream>>>(src, Ah, Wgt, Wut, bg, bu, cw, cb,
                                        XT, X2T, SXT, Hs, Y, AXP, rb, zh,
                                        out, bar, nb);
}